// Round 1
// baseline (691.170 us; speedup 1.0000x reference)
//
#include <hip/hip_runtime.h>
#include <hip/hip_bf16.h>
#include <math.h>

#define D_MODEL 2048
#define NUM_HEADS 16
#define D_K 128
#define SEQ_LEN 4096
#define BATCH 4
#define M_ROWS 16384          // BATCH*SEQ_LEN
#define N_TOT 2304            // 2048 (Q) + 128 (K) + 128 (V)
#define NB_Q 16               // Q blocks of 128 cols (= heads)
#define NB_TOT 18
#define MB_TOT 128            // 16384/128
#define KSTEPS 64             // 2048/32

#define XS_BYTES  134217728ull   // [128 mb][64 t][16KB tile] bf16 hi/lo swizzled
#define WT_BYTES  18874368ull    // [18 nb][64 t][16KB tile]
#define BP_BYTES  16384ull       // permuted bias (2304 floats, padded)
#define ROPE_BYTES 2097152ull    // [4096][128] f32: r1(o)*sqrt(128) || r2(o)*sqrt(128)

typedef __attribute__((ext_vector_type(8))) short bf16x8;
typedef __attribute__((ext_vector_type(8))) unsigned short u16x8;
typedef __attribute__((ext_vector_type(4))) float f32x4;

__device__ __forceinline__ unsigned short f2bf(float f) {
  unsigned int u = __builtin_bit_cast(unsigned int, f);
  u += 0x7fffu + ((u >> 16) & 1u);           // round-to-nearest-even
  return (unsigned short)(u >> 16);
}

__device__ __forceinline__ void async16(const unsigned char* g, unsigned char* l) {
  __builtin_amdgcn_global_load_lds(
      (const __attribute__((address_space(1))) void*)g,
      (__attribute__((address_space(3))) void*)l, 16, 0, 0);
}

// ---------------- pre-pass: rope coefficient table ----------------
// R[s][o]    = sqrt(128) * r1[o](s)   (o in 0..63)
// R[s][64+o] = sqrt(128) * r2[o](s)
// r1[o] = o<32 ? sin(s*th[2o])   : cos(s*th[2(o-32)])
// r2[o] = o<32 ? sin(s*th[2o+1]) : cos(s*th[2(o-32)+1]),  th[j]=10000^(-j/64)
__global__ void rope_kernel(float* __restrict__ ropeT) {
  int idx = blockIdx.x * 256 + threadIdx.x;   // 262144 = 4096*64
  int o = idx & 63;
  int s = idx >> 6;
  int j1 = (o < 32) ? (2 * o) : (2 * (o - 32));
  float th1 = (float)pow(10000.0, -(double)j1 / 64.0);
  float th2 = (float)pow(10000.0, -(double)(j1 + 1) / 64.0);
  float a1 = (float)s * th1;   // match reference's fp32 product rounding
  float a2 = (float)s * th2;
  double v1 = (o < 32) ? sin((double)a1) : cos((double)a1);
  double v2 = (o < 32) ? sin((double)a2) : cos((double)a2);
  const double sc = 11.313708498984760390; // sqrt(128)
  ropeT[s * 128 + o]      = (float)(v1 * sc);
  ropeT[s * 128 + 64 + o] = (float)(v2 * sc);
}

// ---------------- pre-pass: permuted bias ----------------
__global__ void bias_kernel(const float* __restrict__ bq, const float* __restrict__ bk,
                            const float* __restrict__ bv, float* __restrict__ bp) {
  int n = blockIdx.x * 256 + threadIdx.x;   // 2304
  if (n >= N_TOT) return;
  int r = n & 127, nb = n >> 7;
  int d = (r < 64) ? (2 * r) : (2 * (r - 64) + 1);
  float v;
  if (nb < NB_Q)       v = bq[nb * 128 + d];
  else if (nb == NB_Q) v = bk[d];
  else                 v = bv[d];
  bp[n] = v;
}

// ---------------- pre-pass: weights -> bf16 hi/lo, permuted cols, tiled+swizzled ----------------
// tile(nb,t): 128 rows (r = col within block) x 8 chunks of 16B.
// logical chunk c: c<4 -> hi of W[k=t*32+c*8 .. +8][permcol(r)]; c>=4 -> lo.
// stored at chunk position c ^ (r&7).
__global__ void wsplit_kernel(const float* __restrict__ Wq, const float* __restrict__ Wk,
                              const float* __restrict__ Wv, unsigned char* __restrict__ wt) {
  int idx = blockIdx.x * 256 + threadIdx.x;  // 589824 = 18*64*128*4
  int c = idx & 3;
  int r = (idx >> 2) & 127;
  int t = (idx >> 9) & 63;
  int nb = idx >> 15;
  int d = (r < 64) ? (2 * r) : (2 * (r - 64) + 1);
  const float* src; int ld, col;
  if (nb < NB_Q)       { src = Wq; ld = D_MODEL; col = nb * 128 + d; }
  else if (nb == NB_Q) { src = Wk; ld = D_K;     col = d; }
  else                 { src = Wv; ld = D_K;     col = d; }
  int k = t * 32 + c * 8;
  u16x8 H, L;
#pragma unroll
  for (int j = 0; j < 8; j++) {
    float v = src[(size_t)(k + j) * ld + col];
    unsigned short h = f2bf(v);
    float hf = __builtin_bit_cast(float, (unsigned int)h << 16);
    H[j] = h;
    L[j] = f2bf(v - hf);
  }
  unsigned char* tile = wt + (((size_t)(nb * 64 + t)) << 14);
  int sw = r & 7;
  *(u16x8*)(tile + (r * 8 + (c ^ sw)) * 16)       = H;
  *(u16x8*)(tile + (r * 8 + ((c + 4) ^ sw)) * 16) = L;
}

// ---------------- pre-pass: x -> bf16 hi/lo, tiled+swizzled ----------------
__global__ void xsplit_kernel(const float* __restrict__ x, unsigned char* __restrict__ xs) {
  int idx = blockIdx.x * 256 + threadIdx.x;  // 4194304 = 128*64*128*4
  int c = idx & 3;
  int r = (idx >> 2) & 127;
  int t = (idx >> 9) & 63;
  int mb = idx >> 15;
  int m = mb * 128 + r;
  int k = t * 32 + c * 8;
  const float4* p = (const float4*)(x + (size_t)m * D_MODEL + k);
  float4 v0 = p[0], v1 = p[1];
  float v[8] = {v0.x, v0.y, v0.z, v0.w, v1.x, v1.y, v1.z, v1.w};
  u16x8 H, L;
#pragma unroll
  for (int j = 0; j < 8; j++) {
    unsigned short h = f2bf(v[j]);
    float hf = __builtin_bit_cast(float, (unsigned int)h << 16);
    H[j] = h;
    L[j] = f2bf(v[j] - hf);
  }
  unsigned char* tile = xs + (((size_t)(mb * 64 + t)) << 14);
  int sw = r & 7;
  *(u16x8*)(tile + (r * 8 + (c ^ sw)) * 16)       = H;
  *(u16x8*)(tile + (r * 8 + ((c + 4) ^ sw)) * 16) = L;
}

// ---------------- main: bf16x3 GEMM (128x128, BK=32) + fused bias/RoPE epilogue ----------------
__global__ __launch_bounds__(256, 2)
void gemm_rope_kernel(const unsigned char* __restrict__ xs,
                      const unsigned char* __restrict__ wt,
                      const float* __restrict__ bp,
                      const float* __restrict__ ropeT,
                      float* __restrict__ out) {
  __shared__ __align__(16) unsigned char lds[32768];
  unsigned char* ldsA = lds;
  unsigned char* ldsB = lds + 16384;

  const int tid = threadIdx.x;
  const int wave = tid >> 6;
  const int lane = tid & 63;
  const int lr = lane & 15;
  const int g  = lane >> 4;
  const int wm = wave >> 1;   // wave row (0..1) -> 64 rows
  const int wc = wave & 1;    // wave col group: tiles {wc*2, wc*2+1, wc*2+4, wc*2+5}
  const int nb = blockIdx.x;
  const int mb = blockIdx.y;

  // loop-invariant LDS fragment byte offsets (XOR-swizzled, G4 recipe)
  int aoffH[4], aoffL[4], boffH[4], boffL[4];
#pragma unroll
  for (int i = 0; i < 4; i++) {
    int row = wm * 64 + i * 16 + lr;
    int sw = row & 7;
    aoffH[i] = row * 128 + ((g ^ sw) << 4);
    aoffL[i] = row * 128 + (((g + 4) ^ sw) << 4);
  }
#pragma unroll
  for (int a = 0; a < 4; a++) {
    int tn = (a < 2) ? (wc * 2 + a) : (4 + wc * 2 + (a - 2));
    int row = tn * 16 + lr;
    int sw = row & 7;
    boffH[a] = row * 128 + ((g ^ sw) << 4);
    boffL[a] = row * 128 + (((g + 4) ^ sw) << 4);
  }

  f32x4 acc[4][4];
#pragma unroll
  for (int i = 0; i < 4; i++)
#pragma unroll
    for (int a = 0; a < 4; a++)
      acc[i][a] = (f32x4){0.f, 0.f, 0.f, 0.f};

  const unsigned char* abase = xs + (((size_t)(mb * 64)) << 14) + wave * 4096 + lane * 16;
  const unsigned char* bbase = wt + (((size_t)(nb * 64)) << 14) + wave * 4096 + lane * 16;
  unsigned char* ldA = ldsA + wave * 4096;
  unsigned char* ldB = ldsB + wave * 4096;

  for (int t = 0; t < KSTEPS; t++) {
    const unsigned char* asrc = abase + ((size_t)t << 14);
    const unsigned char* bsrc = bbase + ((size_t)t << 14);
#pragma unroll
    for (int j = 0; j < 4; j++) {
      async16(asrc + j * 1024, ldA + j * 1024);
      async16(bsrc + j * 1024, ldB + j * 1024);
    }
    __syncthreads();   // compiler drains vmcnt before s_barrier

    bf16x8 ah[4], al[4], bh[4], bl[4];
#pragma unroll
    for (int i = 0; i < 4; i++) {
      ah[i] = *(const bf16x8*)(ldsA + aoffH[i]);
      al[i] = *(const bf16x8*)(ldsA + aoffL[i]);
    }
#pragma unroll
    for (int a = 0; a < 4; a++) {
      bh[a] = *(const bf16x8*)(ldsB + boffH[a]);
      bl[a] = *(const bf16x8*)(ldsB + boffL[a]);
    }
#pragma unroll
    for (int i = 0; i < 4; i++)
#pragma unroll
      for (int a = 0; a < 4; a++) {
        acc[i][a] = __builtin_amdgcn_mfma_f32_16x16x32_bf16(ah[i], bh[a], acc[i][a], 0, 0, 0);
        acc[i][a] = __builtin_amdgcn_mfma_f32_16x16x32_bf16(ah[i], bl[a], acc[i][a], 0, 0, 0);
        acc[i][a] = __builtin_amdgcn_mfma_f32_16x16x32_bf16(al[i], bh[a], acc[i][a], 0, 0, 0);
      }
    __syncthreads();
  }

  // epilogue: bias + RoPE (pair (o', o'+64) lives in acc[i][a] / acc[i][a+2], same lane)
  const int m0 = mb * 128 + wm * 64;
#pragma unroll
  for (int i = 0; i < 4; i++) {
#pragma unroll
    for (int a = 0; a < 2; a++) {
      int tn = wc * 2 + a;
      int op = tn * 16 + lr;          // o' in [0,64)
      int nlo = nb * 128 + op;
      float blo = bp[nlo];
      float bhi = bp[nlo + 64];
#pragma unroll
      for (int r = 0; r < 4; r++) {
        int row = m0 + i * 16 + g * 4 + r;
        int s = row & (SEQ_LEN - 1);
        int b = row >> 12;
        float t1 = acc[i][a][r]     + blo;   // y[2o']  (+scale folded in R)
        float t2 = acc[i][a + 2][r] + bhi;   // y[2o'+1]
        float R1 = ropeT[s * 128 + op];
        float R2 = ropeT[s * 128 + 64 + op];
        float olo = R1 * t1 - R2 * t2;
        float ohi = R2 * t1 + R1 * t2;
        size_t base;
        if (nb < NB_Q)       base = (((size_t)(b * NUM_HEADS + nb)) * SEQ_LEN + s) * D_K;
        else if (nb == NB_Q) base = (size_t)M_ROWS * D_MODEL
                                    + ((size_t)(b * SEQ_LEN + s)) * D_K;
        else                 base = (size_t)M_ROWS * D_MODEL + (size_t)M_ROWS * D_K
                                    + ((size_t)(b * SEQ_LEN + s)) * D_K;
        out[base + op]      = olo;
        out[base + op + 64] = ohi;
      }
    }
  }
}

extern "C" void kernel_launch(void* const* d_in, const int* in_sizes, int n_in,
                              void* d_out, int out_size, void* d_ws, size_t ws_size,
                              hipStream_t stream) {
  const float* x  = (const float*)d_in[0];
  const float* Wq = (const float*)d_in[1];
  const float* bq = (const float*)d_in[2];
  const float* Wk = (const float*)d_in[3];
  const float* bk = (const float*)d_in[4];
  const float* Wv = (const float*)d_in[5];
  const float* bv = (const float*)d_in[6];
  float* out = (float*)d_out;

  unsigned char* ws = (unsigned char*)d_ws;
  unsigned char* xs = ws;
  unsigned char* wt = ws + XS_BYTES;
  float* bp    = (float*)(ws + XS_BYTES + WT_BYTES);
  float* ropeT = (float*)(ws + XS_BYTES + WT_BYTES + BP_BYTES);
  // total ws needed: 155,205,632 bytes

  rope_kernel<<<1024, 256, 0, stream>>>(ropeT);
  bias_kernel<<<9, 256, 0, stream>>>(bq, bk, bv, bp);
  wsplit_kernel<<<2304, 256, 0, stream>>>(Wq, Wk, Wv, wt);
  xsplit_kernel<<<16384, 256, 0, stream>>>(x, xs);
  dim3 grid(NB_TOT, MB_TOT);
  gemm_rope_kernel<<<grid, 256, 0, stream>>>(xs, wt, bp, ropeT, out);
}

// Round 2
// 582.771 us; speedup vs baseline: 1.1860x; 1.1860x over previous
//
#include <hip/hip_runtime.h>
#include <hip/hip_bf16.h>
#include <math.h>

#define D_MODEL 2048
#define NUM_HEADS 16
#define D_K 128
#define SEQ_LEN 4096
#define BATCH 4
#define M_ROWS 16384          // BATCH*SEQ_LEN
#define N_TOT 2304            // 2048 (Q) + 128 (K) + 128 (V)
#define NB_Q 16               // Q col-blocks of 128 (= heads)
#define NB_TOT 18             // 128-col blocks
#define MB_TOT 64             // 256-row blocks
#define KSLICES 64            // 2048 / 32

#define XB_BYTES 67108864ull     // [64 mb][64 s][16KB] x as plain bf16, tiled+swizzled
#define WT_BYTES 18874368ull     // [18 nb][64 s][16KB] W hi/lo, permuted cols, swizzled
#define BP_BYTES 16384ull        // permuted bias

typedef __attribute__((ext_vector_type(8))) short bf16x8;
typedef __attribute__((ext_vector_type(8))) unsigned short u16x8;
typedef __attribute__((ext_vector_type(4))) float f32x4;

__device__ __forceinline__ unsigned short f2bf(float f) {
  unsigned int u = __builtin_bit_cast(unsigned int, f);
  u += 0x7fffu + ((u >> 16) & 1u);           // round-to-nearest-even
  return (unsigned short)(u >> 16);
}

__device__ __forceinline__ void async16(const unsigned char* g, unsigned char* l) {
  __builtin_amdgcn_global_load_lds(
      (const __attribute__((address_space(1))) void*)g,
      (__attribute__((address_space(3))) void*)l, 16, 0, 0);
}

// ---------------- pre-pass: rope coefficient table (fp32 ocml to match XLA) ----------------
// R[s][o]    = sqrt(128) * r1[o](s)   (o in 0..63)
// R[s][64+o] = sqrt(128) * r2[o](s)
__global__ void rope_kernel(float* __restrict__ ropeT) {
  int idx = blockIdx.x * 256 + threadIdx.x;   // 262144 = 4096*64
  int o = idx & 63;
  int sp = idx >> 6;
  int j1 = (o < 32) ? (2 * o) : (2 * (o - 32));
  // reference: theta = 1.0 / power(10000, j/64) computed in fp32
  float th1 = 1.0f / powf(10000.0f, (float)j1 / 64.0f);
  float th2 = 1.0f / powf(10000.0f, (float)(j1 + 1) / 64.0f);
  float a1 = (float)sp * th1;
  float a2 = (float)sp * th2;
  float v1 = (o < 32) ? sinf(a1) : cosf(a1);
  float v2 = (o < 32) ? sinf(a2) : cosf(a2);
  const float sc = 11.3137084989847604f; // sqrt(128)
  ropeT[sp * 128 + o]      = v1 * sc;
  ropeT[sp * 128 + 64 + o] = v2 * sc;
}

// ---------------- pre-pass: permuted bias ----------------
__global__ void bias_kernel(const float* __restrict__ bq, const float* __restrict__ bk,
                            const float* __restrict__ bv, float* __restrict__ bp) {
  int n = blockIdx.x * 256 + threadIdx.x;   // 2304
  if (n >= N_TOT) return;
  int r = n & 127, nb = n >> 7;
  int d = (r < 64) ? (2 * r) : (2 * (r - 64) + 1);
  float v;
  if (nb < NB_Q)       v = bq[nb * 128 + d];
  else if (nb == NB_Q) v = bk[d];
  else                 v = bv[d];
  bp[n] = v;
}

// ---------------- pre-pass: W -> bf16 hi/lo, permuted cols, tiled+swizzled ----------------
// tile(nb,t): 128 rows (r = col within block) x 8 chunks of 16B (hi c=0..3, lo c=4..7),
// chunk stored at position c ^ (r&7).  (unchanged from round 1 — proven 0-conflict)
__global__ void wsplit_kernel(const float* __restrict__ Wq, const float* __restrict__ Wk,
                              const float* __restrict__ Wv, unsigned char* __restrict__ wt) {
  int idx = blockIdx.x * 256 + threadIdx.x;  // 589824 = 18*64*128*4
  int c = idx & 3;
  int r = (idx >> 2) & 127;
  int t = (idx >> 9) & 63;
  int nb = idx >> 15;
  int d = (r < 64) ? (2 * r) : (2 * (r - 64) + 1);
  const float* src; int ld, col;
  if (nb < NB_Q)       { src = Wq; ld = D_MODEL; col = nb * 128 + d; }
  else if (nb == NB_Q) { src = Wk; ld = D_K;     col = d; }
  else                 { src = Wv; ld = D_K;     col = d; }
  int k = t * 32 + c * 8;
  u16x8 H, L;
#pragma unroll
  for (int j = 0; j < 8; j++) {
    float v = src[(size_t)(k + j) * ld + col];
    unsigned short h = f2bf(v);
    float hf = __builtin_bit_cast(float, (unsigned int)h << 16);
    H[j] = h;
    L[j] = f2bf(v - hf);
  }
  unsigned char* tile = wt + (((size_t)(nb * 64 + t)) << 14);
  int sw = r & 7;
  *(u16x8*)(tile + (r * 8 + (c ^ sw)) * 16)       = H;
  *(u16x8*)(tile + (r * 8 + ((c + 4) ^ sw)) * 16) = L;
}

// ---------------- pre-pass: x -> plain bf16, tiled+swizzled ----------------
// tile(mb,s): 256 rows x 4 chunks of 16B (K-groups), chunk at position c ^ ((r>>1)&3)
// (2-row bank period of the 64B row -> wave b128 reads are 2-way max = free, m136)
__global__ void xcast_kernel(const float* __restrict__ x, unsigned char* __restrict__ xb) {
  int idx = blockIdx.x * 256 + threadIdx.x;  // 4,194,304 = 64*64*256*4
  int c = idx & 3;
  int r = (idx >> 2) & 255;
  int sid = (idx >> 10) & 63;
  int mb = idx >> 16;
  const float4* p = (const float4*)(x + (size_t)(mb * 256 + r) * D_MODEL + sid * 32 + c * 8);
  float4 v0 = p[0], v1 = p[1];
  float v[8] = {v0.x, v0.y, v0.z, v0.w, v1.x, v1.y, v1.z, v1.w};
  u16x8 H;
#pragma unroll
  for (int j = 0; j < 8; j++) H[j] = f2bf(v[j]);
  unsigned char* tile = xb + (((size_t)(mb * 64 + sid)) << 14);
  *(u16x8*)(tile + r * 64 + ((c ^ ((r >> 1) & 3)) << 4)) = H;
}

// ---------------- main: bf16x2 GEMM (256x128, BK=32, 4-slot LDS ring, counted vmcnt)
//                 + fused bias/RoPE epilogue ----------------
__global__ __launch_bounds__(512, 2)
void gemm_rope_kernel(const unsigned char* __restrict__ xb,
                      const unsigned char* __restrict__ wt,
                      const float* __restrict__ bp,
                      const float* __restrict__ ropeT,
                      float* __restrict__ out) {
  __shared__ __align__(16) unsigned char lds[131072];   // 4 slots x (A 16K + B 16K)

  const int tid = threadIdx.x;
  const int wave = tid >> 6;
  const int lane = tid & 63;
  const int lr = lane & 15;
  const int g  = lane >> 4;
  const int wm = wave >> 1;   // 0..3 -> 64-row band
  const int wn = wave & 1;    // 0..1 -> 64-col band (split across rope-pair halves)

  // XCD-aware bijective swizzle: 1152 = 8 * 144; logical order nb-major (B reuse per XCD L2)
  int L = (blockIdx.x & 7) * 144 + (blockIdx.x >> 3);
  const int nb = L >> 6;
  const int mb = L & 63;

  // loop-invariant LDS fragment byte offsets
  int aoff[4], boff[4];
#pragma unroll
  for (int i = 0; i < 4; i++) {
    int row = wm * 64 + i * 16 + lr;
    aoff[i] = row * 64 + ((g ^ ((row >> 1) & 3)) << 4);
  }
#pragma unroll
  for (int a = 0; a < 4; a++) {
    int tn = (a < 2) ? (2 * wn + a) : (4 + 2 * wn + (a - 2));
    int row = tn * 16 + lr;
    boff[a] = 16384 + row * 128 + ((g ^ (row & 7)) << 4);   // lo fragment at ^64
  }

  f32x4 acc[4][4];
#pragma unroll
  for (int i = 0; i < 4; i++)
#pragma unroll
    for (int a = 0; a < 4; a++)
      acc[i][a] = (f32x4){0.f, 0.f, 0.f, 0.f};

  const unsigned char* ga0 = xb + (((size_t)(mb * 64)) << 14) + tid * 16;  // per-lane global
  const unsigned char* gb0 = wt + (((size_t)(nb * 64)) << 14) + tid * 16;
  unsigned char* lwave = lds + wave * 1024;                                // wave-uniform LDS

#define ISSUE(s2)                                                   \
  do {                                                              \
    unsigned char* ld_ = lwave + ((s2) & 3) * 32768;                \
    const unsigned char* ga_ = ga0 + ((size_t)(s2) << 14);          \
    const unsigned char* gb_ = gb0 + ((size_t)(s2) << 14);          \
    async16(ga_,        ld_);                                       \
    async16(ga_ + 8192, ld_ + 8192);                                \
    async16(gb_,        ld_ + 16384);                               \
    async16(gb_ + 8192, ld_ + 24576);                               \
  } while (0)

  ISSUE(0); ISSUE(1); ISSUE(2);   // depth-3 prologue

  for (int s = 0; s < KSLICES; ++s) {
    // boundary: per-wave counted wait (slice s landed; s+1,s+2 stay in flight), then barrier
    if (s < KSLICES - 2)       asm volatile("s_waitcnt vmcnt(8)" ::: "memory");
    else if (s == KSLICES - 2) asm volatile("s_waitcnt vmcnt(4)" ::: "memory");
    else                       asm volatile("s_waitcnt vmcnt(0)" ::: "memory");
    __builtin_amdgcn_s_barrier();
    __builtin_amdgcn_sched_barrier(0);

    if (s + 3 < KSLICES) ISSUE(s + 3);   // slot (s+3)&3 == slot (s-1)&3: freed at this barrier

    const unsigned char* sl = lds + (s & 3) * 32768;
    bf16x8 af[4], bh[4], bl[4];
#pragma unroll
    for (int i = 0; i < 4; i++) af[i] = *(const bf16x8*)(sl + aoff[i]);
#pragma unroll
    for (int a = 0; a < 4; a++) {
      bh[a] = *(const bf16x8*)(sl + boff[a]);
      bl[a] = *(const bf16x8*)(sl + (boff[a] ^ 64));
    }

    __builtin_amdgcn_s_setprio(1);
#pragma unroll
    for (int a = 0; a < 4; a++)
#pragma unroll
      for (int i = 0; i < 4; i++) {
        acc[i][a] = __builtin_amdgcn_mfma_f32_16x16x32_bf16(af[i], bh[a], acc[i][a], 0, 0, 0);
        acc[i][a] = __builtin_amdgcn_mfma_f32_16x16x32_bf16(af[i], bl[a], acc[i][a], 0, 0, 0);
      }
    __builtin_amdgcn_s_setprio(0);
  }
#undef ISSUE

  // epilogue: bias + RoPE; pair (o', o'+64) lives in acc[i][a] / acc[i][a+2], same lane
  const int m0 = mb * 256 + wm * 64;
#pragma unroll
  for (int i = 0; i < 4; i++) {
#pragma unroll
    for (int a = 0; a < 2; a++) {
      int op = 32 * wn + a * 16 + lr;     // o' in [0,64)
      int nlo = nb * 128 + op;
      float blo = bp[nlo];
      float bhi = bp[nlo + 64];
#pragma unroll
      for (int r = 0; r < 4; r++) {
        int row = m0 + i * 16 + g * 4 + r;
        int sp = row & (SEQ_LEN - 1);
        int b = row >> 12;
        float t1 = acc[i][a][r]     + blo;   // y[2o']   (scale folded into R)
        float t2 = acc[i][a + 2][r] + bhi;   // y[2o'+1]
        float R1 = ropeT[sp * 128 + op];
        float R2 = ropeT[sp * 128 + 64 + op];
        float olo = R1 * t1 - R2 * t2;
        float ohi = R2 * t1 + R1 * t2;
        size_t base;
        if (nb < NB_Q)       base = (((size_t)(b * NUM_HEADS + nb)) * SEQ_LEN + sp) * D_K;
        else if (nb == NB_Q) base = (size_t)M_ROWS * D_MODEL
                                    + ((size_t)(b * SEQ_LEN + sp)) * D_K;
        else                 base = (size_t)M_ROWS * D_MODEL + (size_t)M_ROWS * D_K
                                    + ((size_t)(b * SEQ_LEN + sp)) * D_K;
        out[base + op]      = olo;
        out[base + op + 64] = ohi;
      }
    }
  }
}

extern "C" void kernel_launch(void* const* d_in, const int* in_sizes, int n_in,
                              void* d_out, int out_size, void* d_ws, size_t ws_size,
                              hipStream_t stream) {
  const float* x  = (const float*)d_in[0];
  const float* Wq = (const float*)d_in[1];
  const float* bq = (const float*)d_in[2];
  const float* Wk = (const float*)d_in[3];
  const float* bk = (const float*)d_in[4];
  const float* Wv = (const float*)d_in[5];
  const float* bv = (const float*)d_in[6];
  float* out = (float*)d_out;

  unsigned char* ws = (unsigned char*)d_ws;
  unsigned char* xb = ws;
  unsigned char* wt = ws + XB_BYTES;
  float* bp    = (float*)(ws + XB_BYTES + WT_BYTES);
  float* ropeT = (float*)(ws + XB_BYTES + WT_BYTES + BP_BYTES);
  // total ws needed: ~88 MB

  rope_kernel<<<1024, 256, 0, stream>>>(ropeT);
  bias_kernel<<<9, 256, 0, stream>>>(bq, bk, bv, bp);
  wsplit_kernel<<<2304, 256, 0, stream>>>(Wq, Wk, Wv, wt);
  xcast_kernel<<<16384, 256, 0, stream>>>(x, xb);
  gemm_rope_kernel<<<1152, 512, 0, stream>>>(xb, wt, bp, ropeT, out);
}

// Round 3
// 446.150 us; speedup vs baseline: 1.5492x; 1.3062x over previous
//
#include <hip/hip_runtime.h>
#include <hip/hip_bf16.h>
#include <math.h>

#define D_MODEL 2048
#define NUM_HEADS 16
#define D_K 128
#define SEQ_LEN 4096
#define BATCH 4
#define M_ROWS 16384          // BATCH*SEQ_LEN
#define N_TOT 2304            // 2048 (Q) + 128 (K) + 128 (V)
#define KT 32                 // K-tiles of 64 (2048/64)

#define XB_BYTES 67108864ull  // [64 mb][32 kt][32KB tile] x bf16, swizzled LDS image
#define WT_BYTES 9437184ull   // [9 nb2][32 kt][32KB tile] W bf16, stripe-permuted, swizzled
#define BP_BYTES 16384ull     // permuted bias

typedef __attribute__((ext_vector_type(8))) short bf16x8;
typedef __attribute__((ext_vector_type(8))) unsigned short u16x8;
typedef __attribute__((ext_vector_type(4))) float f32x4;

__device__ __forceinline__ unsigned short f2bf(float f) {
  unsigned int u = __builtin_bit_cast(unsigned int, f);
  u += 0x7fffu + ((u >> 16) & 1u);
  return (unsigned short)(u >> 16);
}

__device__ __forceinline__ void async16(const unsigned char* g, unsigned char* l) {
  __builtin_amdgcn_global_load_lds(
      (const __attribute__((address_space(1))) void*)g,
      (__attribute__((address_space(3))) void*)l, 16, 0, 0);
}

// ---------------- rope coefficient table ----------------
__global__ void rope_kernel(float* __restrict__ ropeT) {
  int idx = blockIdx.x * 256 + threadIdx.x;   // 262144 = 4096*64
  int o = idx & 63;
  int sp = idx >> 6;
  int j1 = (o < 32) ? (2 * o) : (2 * (o - 32));
  float th1 = 1.0f / powf(10000.0f, (float)j1 / 64.0f);
  float th2 = 1.0f / powf(10000.0f, (float)(j1 + 1) / 64.0f);
  float a1 = (float)sp * th1;
  float a2 = (float)sp * th2;
  float v1 = (o < 32) ? sinf(a1) : cosf(a1);
  float v2 = (o < 32) ? sinf(a2) : cosf(a2);
  const float sc = 11.3137084989847604f; // sqrt(128)
  ropeT[sp * 128 + o]      = v1 * sc;
  ropeT[sp * 128 + 64 + o] = v2 * sc;
}

// ---------------- permuted bias ----------------
__global__ void bias_kernel(const float* __restrict__ bq, const float* __restrict__ bk,
                            const float* __restrict__ bv, float* __restrict__ bp) {
  int n = blockIdx.x * 256 + threadIdx.x;   // 2304
  if (n >= N_TOT) return;
  int r = n & 127, nb = n >> 7;
  int d = (r < 64) ? (2 * r) : (2 * (r - 64) + 1);
  float v;
  if (nb < 16)       v = bq[nb * 128 + d];
  else if (nb == 16) v = bk[d];
  else               v = bv[d];
  bp[n] = v;
}

// ---------------- W -> bf16, stripe-permuted cols, tiled+swizzled ----------------
// tile(nb2,kt): 256 LDS-rows x 8 chunks of 16B. LDS-row R encodes (wng,a,lr):
//   wng=R>>6, a=(R>>4)&3, lr=R&15; s=wng>>1, w=wng&1; t=2w+(a&1)+4*(a>>1)
//   col-in-128 = t*16+lr; d = even/odd permute; n = (nb2*2+s)*128+d
// chunk c (k-octet of K64) stored at position c ^ (R&7).
__global__ void wsplit_kernel(const float* __restrict__ Wq, const float* __restrict__ Wk,
                              const float* __restrict__ Wv, unsigned char* __restrict__ wt) {
  int R = threadIdx.x;
  int c   = blockIdx.x & 7;
  int kt  = (blockIdx.x >> 3) & 31;
  int nb2 = blockIdx.x >> 8;         // grid = 9*256
  int wng = R >> 6, q = R & 63, a = q >> 4, lr = q & 15;
  int s = wng >> 1, w = wng & 1;
  int tq = 2 * w + (a & 1) + 4 * (a >> 1);
  int col = tq * 16 + lr;
  int d = (col < 64) ? (2 * col) : (2 * (col - 64) + 1);
  int n = (nb2 * 2 + s) * 128 + d;
  const float* src; int ld, cc;
  if (n < 2048)      { src = Wq; ld = 2048; cc = n; }
  else if (n < 2176) { src = Wk; ld = 128;  cc = n - 2048; }
  else               { src = Wv; ld = 128;  cc = n - 2176; }
  int k0 = kt * 64 + c * 8;
  u16x8 H;
#pragma unroll
  for (int j = 0; j < 8; j++) H[j] = f2bf(src[(size_t)(k0 + j) * ld + cc]);
  unsigned char* tile = wt + (((size_t)(nb2 * 32 + kt)) << 15);
  *(u16x8*)(tile + R * 128 + ((c ^ (R & 7)) << 4)) = H;
}

// ---------------- x -> bf16, tiled+swizzled ----------------
// tile(mb,kt): 256 rows x 8 chunks (k-octets), chunk at c ^ (r&7)
__global__ void xcast_kernel(const float* __restrict__ x, unsigned char* __restrict__ xb) {
  int idx = blockIdx.x * 256 + threadIdx.x;  // 4,194,304 = 64*32*256*8
  int c  = idx & 7;
  int r  = (idx >> 3) & 255;
  int kt = (idx >> 11) & 31;
  int mb = idx >> 16;
  const float4* p = (const float4*)(x + ((size_t)(mb * 256 + r)) * D_MODEL + kt * 64 + c * 8);
  float4 v0 = p[0], v1 = p[1];
  float v[8] = {v0.x, v0.y, v0.z, v0.w, v1.x, v1.y, v1.z, v1.w};
  u16x8 H;
#pragma unroll
  for (int j = 0; j < 8; j++) H[j] = f2bf(v[j]);
  unsigned char* tile = xb + (((size_t)(mb * 32 + kt)) << 15);
  *(u16x8*)(tile + r * 128 + ((c ^ (r & 7)) << 4)) = H;
}

// ---------------- main: 256x256x64 8-wave 4-phase pipelined bf16 GEMM + RoPE ----------------
// Staging/consumption invariants (per wave, per group t computing tile t, staging t+1):
//   issue order: ph0:B0,B1  ph1:B2,B3  ph2:A0,A1  ph3:A2,A3   (8 x 1KB gloads)
//   A share j covers rows wm*128 + j*32 + wng*8 (union over wng = 32-row group j)
//   B share j covers stripe-rows wng*64 + wm*32 + j*8 (union = all 256)
//   phase p reads A rows [band+32p,+32) (frags 2p,2p+1) ; phase 0 reads ALL B
//   end-of-phase waits (outstanding after wait):
//     ph0->4  ph1->5  ph2->6  ph3->3(boundary)   [tail group: 2,1,0,0]
__global__ __launch_bounds__(512, 2)
void gemm_rope_kernel(const unsigned char* __restrict__ xb,
                      const unsigned char* __restrict__ wt,
                      const float* __restrict__ bp,
                      const float* __restrict__ ropeT,
                      float* __restrict__ out) {
  __shared__ __align__(16) unsigned char lds[131072];  // 2 slots x (A 32K | B 32K)

  const int tid = threadIdx.x;
  const int wave = tid >> 6, lane = tid & 63;
  const int lr = lane & 15, gl = lane >> 4;
  const int wm = wave >> 2;     // 0..1: 128-row band
  const int wng = wave & 3;     // 0..3: 64-row B stripe

  int bid = blockIdx.x;                      // 576 = 8 * 72 (bijective XCD swizzle)
  int wg = (bid & 7) * 72 + (bid >> 3);
  const int mb  = wg / 9;
  const int nb2 = wg % 9;

  const int sw = lr & 7;
  int aoff[8], boff[4];
#pragma unroll
  for (int i = 0; i < 8; i++)
    aoff[i] = (wm * 128 + i * 16 + lr) * 128 + ((gl ^ sw) << 4);
#pragma unroll
  for (int a = 0; a < 4; a++)
    boff[a] = 32768 + (wng * 64 + a * 16 + lr) * 128 + ((gl ^ sw) << 4);

  f32x4 acc[8][4];
#pragma unroll
  for (int i = 0; i < 8; i++)
#pragma unroll
    for (int a = 0; a < 4; a++) acc[i][a] = (f32x4){0.f, 0.f, 0.f, 0.f};

  const unsigned char* gA = xb + ((size_t)(mb * KT) << 15);
  const unsigned char* gB = wt + ((size_t)(nb2 * KT) << 15);
  const int aro = wm * 16384 + wng * 1024;   // + j*4096
  const int bro = wng * 8192 + wm * 4096;    // + j*1024

  // prologue: stage tile 0 (B0..B3 then A0..A3), wait B+A0, barrier
#pragma unroll
  for (int j = 0; j < 4; j++)
    async16(gB + bro + j * 1024 + lane * 16, lds + 32768 + bro + j * 1024);
#pragma unroll
  for (int j = 0; j < 4; j++)
    async16(gA + aro + j * 4096 + lane * 16, lds + aro + j * 4096);
  asm volatile("s_waitcnt vmcnt(3)" ::: "memory");
  __builtin_amdgcn_s_barrier();
  __builtin_amdgcn_sched_barrier(0);

#define PHASE_BODY(p, CS, STAGE, K)                                                        \
  {                                                                                        \
    bf16x8 x0h = *(const bf16x8*)(lds + (CS) + aoff[2*(p)]);                               \
    bf16x8 x0l = *(const bf16x8*)(lds + (CS) + (aoff[2*(p)] ^ 64));                        \
    bf16x8 x1h = *(const bf16x8*)(lds + (CS) + aoff[2*(p)+1]);                             \
    bf16x8 x1l = *(const bf16x8*)(lds + (CS) + (aoff[2*(p)+1] ^ 64));                      \
    STAGE                                                                                  \
    __builtin_amdgcn_s_setprio(1);                                                         \
    _Pragma("unroll")                                                                      \
    for (int a_ = 0; a_ < 4; ++a_) {                                                       \
      acc[2*(p)][a_]   = __builtin_amdgcn_mfma_f32_16x16x32_bf16(x0h, bh[a_], acc[2*(p)][a_], 0,0,0);   \
      acc[2*(p)][a_]   = __builtin_amdgcn_mfma_f32_16x16x32_bf16(x0l, bl[a_], acc[2*(p)][a_], 0,0,0);   \
      acc[2*(p)+1][a_] = __builtin_amdgcn_mfma_f32_16x16x32_bf16(x1h, bh[a_], acc[2*(p)+1][a_], 0,0,0); \
      acc[2*(p)+1][a_] = __builtin_amdgcn_mfma_f32_16x16x32_bf16(x1l, bl[a_], acc[2*(p)+1][a_], 0,0,0); \
    }                                                                                      \
    __builtin_amdgcn_s_setprio(0);                                                         \
    asm volatile("s_waitcnt vmcnt(" K ")" ::: "memory");                                   \
    __builtin_amdgcn_s_barrier();                                                          \
    __builtin_amdgcn_sched_barrier(0);                                                     \
  }

#define STAGE_B01 { async16(gBn + bro + lane*16, lB + bro);                 \
                    async16(gBn + bro + 1024 + lane*16, lB + bro + 1024); }
#define STAGE_B23 { async16(gBn + bro + 2048 + lane*16, lB + bro + 2048);   \
                    async16(gBn + bro + 3072 + lane*16, lB + bro + 3072); }
#define STAGE_A01 { async16(gAn + aro + lane*16, lA + aro);                 \
                    async16(gAn + aro + 4096 + lane*16, lA + aro + 4096); }
#define STAGE_A23 { async16(gAn + aro + 8192 + lane*16, lA + aro + 8192);   \
                    async16(gAn + aro + 12288 + lane*16, lA + aro + 12288); }
#define STAGE_NONE {}

  for (int t = 0; t < KT - 1; ++t) {
    const int CS = (t & 1) << 16;
    unsigned char* lA = lds + (CS ^ 65536);
    unsigned char* lB = lA + 32768;
    const unsigned char* gAn = gA + ((size_t)(t + 1) << 15);
    const unsigned char* gBn = gB + ((size_t)(t + 1) << 15);
    bf16x8 bh[4], bl[4];
#pragma unroll
    for (int a = 0; a < 4; a++) {
      bh[a] = *(const bf16x8*)(lds + CS + boff[a]);
      bl[a] = *(const bf16x8*)(lds + CS + (boff[a] ^ 64));
    }
    PHASE_BODY(0, CS, STAGE_B01, "4")
    PHASE_BODY(1, CS, STAGE_B23, "5")
    PHASE_BODY(2, CS, STAGE_A01, "6")
    PHASE_BODY(3, CS, STAGE_A23, "3")
  }
  { // tail group (tile KT-1): no staging, progressive drain
    const int CS = ((KT - 1) & 1) << 16;
    bf16x8 bh[4], bl[4];
#pragma unroll
    for (int a = 0; a < 4; a++) {
      bh[a] = *(const bf16x8*)(lds + CS + boff[a]);
      bl[a] = *(const bf16x8*)(lds + CS + (boff[a] ^ 64));
    }
    PHASE_BODY(0, CS, STAGE_NONE, "2")
    PHASE_BODY(1, CS, STAGE_NONE, "1")
    PHASE_BODY(2, CS, STAGE_NONE, "0")
    PHASE_BODY(3, CS, STAGE_NONE, "0")
  }
#undef PHASE_BODY
#undef STAGE_B01
#undef STAGE_B23
#undef STAGE_A01
#undef STAGE_A23
#undef STAGE_NONE

  // epilogue: bias + RoPE; pair (o', o'+64) = acc[i][a] / acc[i][a+2], same lane
  const int m0 = mb * 256 + wm * 128;
  const int ssub = wng >> 1, w = wng & 1;
  const int nbv = nb2 * 2 + ssub;          // 128-col block 0..17
#pragma unroll
  for (int i = 0; i < 8; i++) {
#pragma unroll
    for (int a = 0; a < 2; a++) {
      int op = (2 * w + a) * 16 + lr;      // o' in [0,64)
      int nlo = nbv * 128 + op;
      float blo = bp[nlo], bhi = bp[nlo + 64];
#pragma unroll
      for (int r = 0; r < 4; r++) {
        int row = m0 + i * 16 + gl * 4 + r;
        int sp = row & (SEQ_LEN - 1);
        int b = row >> 12;
        float t1 = acc[i][a][r]     + blo;
        float t2 = acc[i][a + 2][r] + bhi;
        float R1 = ropeT[sp * 128 + op];
        float R2 = ropeT[sp * 128 + 64 + op];
        float olo = R1 * t1 - R2 * t2;
        float ohi = R2 * t1 + R1 * t2;
        size_t base;
        if (nbv < 16)       base = (((size_t)(b * NUM_HEADS + nbv)) * SEQ_LEN + sp) * D_K;
        else if (nbv == 16) base = (size_t)M_ROWS * D_MODEL
                                   + ((size_t)(b * SEQ_LEN + sp)) * D_K;
        else                base = (size_t)M_ROWS * D_MODEL + (size_t)M_ROWS * D_K
                                   + ((size_t)(b * SEQ_LEN + sp)) * D_K;
        out[base + op]      = olo;
        out[base + op + 64] = ohi;
      }
    }
  }
}

extern "C" void kernel_launch(void* const* d_in, const int* in_sizes, int n_in,
                              void* d_out, int out_size, void* d_ws, size_t ws_size,
                              hipStream_t stream) {
  const float* x  = (const float*)d_in[0];
  const float* Wq = (const float*)d_in[1];
  const float* bq = (const float*)d_in[2];
  const float* Wk = (const float*)d_in[3];
  const float* bk = (const float*)d_in[4];
  const float* Wv = (const float*)d_in[5];
  const float* bv = (const float*)d_in[6];
  float* out = (float*)d_out;

  unsigned char* ws = (unsigned char*)d_ws;
  unsigned char* xb = ws;
  unsigned char* wt = ws + XB_BYTES;
  float* bp    = (float*)(ws + XB_BYTES + WT_BYTES);
  float* ropeT = (float*)(ws + XB_BYTES + WT_BYTES + BP_BYTES);
  // ws needed: ~79 MB

  rope_kernel<<<1024, 256, 0, stream>>>(ropeT);
  bias_kernel<<<9, 256, 0, stream>>>(bq, bk, bv, bp);
  wsplit_kernel<<<2304, 256, 0, stream>>>(Wq, Wk, Wv, wt);
  xcast_kernel<<<16384, 256, 0, stream>>>(x, xb);
  gemm_rope_kernel<<<576, 512, 0, stream>>>(xb, wt, bp, ropeT, out);
}